// Round 3
// baseline (73.503 us; speedup 1.0000x reference)
//
#include <hip/hip_runtime.h>
#include <hip/hip_bf16.h>
#include <stdint.h>

typedef __attribute__((ext_vector_type(8))) short short8;
typedef __attribute__((ext_vector_type(4))) float f32x4;

__device__ __forceinline__ unsigned int f2bf(float f) {
    unsigned int u = __float_as_uint(f);
    return (u + 0x7fffu + ((u >> 16) & 1u)) >> 16;   // RNE fp32 -> bf16
}

// ---- kernel 1: fp32 -> bf16 (linear layout) + per-row squared norms ----
__global__ void prep_kernel(const float* __restrict__ emb,
                            unsigned short* __restrict__ ebs,
                            float* __restrict__ sq, int n) {
    int t = threadIdx.x;
    int row = blockIdx.x * 16 + (t >> 4);
    int c   = t & 15;
    if (row >= n) return;
    const float* src = emb + (size_t)row * 128 + c * 8;
    float4 f0 = *reinterpret_cast<const float4*>(src);
    float4 f1 = *reinterpret_cast<const float4*>(src + 4);
    uint4 wv;
    wv.x = f2bf(f0.x) | (f2bf(f0.y) << 16);
    wv.y = f2bf(f0.z) | (f2bf(f0.w) << 16);
    wv.z = f2bf(f1.x) | (f2bf(f1.y) << 16);
    wv.w = f2bf(f1.z) | (f2bf(f1.w) << 16);
    *reinterpret_cast<uint4*>(reinterpret_cast<char*>(ebs) + row * 256 + c * 16) = wv;
    float p = f0.x*f0.x + f0.y*f0.y + f0.z*f0.z + f0.w*f0.w
            + f1.x*f1.x + f1.y*f1.y + f1.z*f1.z + f1.w*f1.w;
    #pragma unroll
    for (int off = 1; off < 16; off <<= 1) p += __shfl_xor(p, off);
    if (c == 0) sq[row] = p;
}

// ---- kernel 2: barrier-free gram tile + fused loss epilogue ----
// Fragments are read directly from global (data is L2-resident, 2 MB).
__launch_bounds__(256, 4)
__global__ void loss_kernel(const unsigned short* __restrict__ ebs,
                            const int* __restrict__ labels,
                            const float* __restrict__ sq,
                            float* __restrict__ accum, int nt) {
    __shared__ float wsum[4];

    // linear block id -> upper-triangular tile (bi, bj), bj >= bi
    int tt = blockIdx.x, bi = 0;
    while (tt >= nt - bi) { tt -= nt - bi; ++bi; }
    int bj = bi + tt;
    int rowBase = bi << 7, colBase = bj << 7;
    bool diag = (bi == bj);

    int t = threadIdx.x, lane = t & 63, w = t >> 6;
    int wr = (w >> 1) << 6, wc = (w & 1) << 6;   // 64x64 quadrant per wave
    int fr = lane & 15, kg = lane >> 4;

    const char* base = reinterpret_cast<const char*>(ebs);
    // per-lane row byte bases for the 8 fragment streams
    const char* aRow[4];
    const char* bRow[4];
    #pragma unroll
    for (int m = 0; m < 4; ++m)
        aRow[m] = base + (size_t)(rowBase + wr + m * 16 + fr) * 256;
    #pragma unroll
    for (int n = 0; n < 4; ++n)
        bRow[n] = base + (size_t)(colBase + wc + n * 16 + fr) * 256;

    f32x4 acc[4][4];
    const f32x4 zero = {0.0f, 0.0f, 0.0f, 0.0f};
    #pragma unroll
    for (int m = 0; m < 4; ++m)
        #pragma unroll
        for (int n = 0; n < 4; ++n) acc[m][n] = zero;

    #pragma unroll
    for (int kk = 0; kk < 4; ++kk) {
        int koff = kk * 64 + kg * 16;        // byte offset of this lane's k-chunk
        short8 a[4], b[4];
        #pragma unroll
        for (int m = 0; m < 4; ++m)
            a[m] = *reinterpret_cast<const short8*>(aRow[m] + koff);
        #pragma unroll
        for (int n = 0; n < 4; ++n)
            b[n] = *reinterpret_cast<const short8*>(bRow[n] + koff);
        #pragma unroll
        for (int m = 0; m < 4; ++m)
            #pragma unroll
            for (int n = 0; n < 4; ++n)
                acc[m][n] = __builtin_amdgcn_mfma_f32_16x16x32_bf16(
                                a[m], b[n], acc[m][n], 0, 0, 0);
    }

    // epilogue: C/D layout col=lane&15, row=(lane>>4)*4+reg
    bool offdiag = !diag;
    float sqj[4]; int labj[4];
    #pragma unroll
    for (int n = 0; n < 4; ++n) {
        int j  = colBase + wc + n * 16 + fr;
        sqj[n]  = sq[j];
        labj[n] = labels[j];
    }
    float local = 0.0f;
    #pragma unroll
    for (int m = 0; m < 4; ++m) {
        int i0 = rowBase + wr + m * 16 + kg * 4;   // 4 consecutive rows
        float4 sqi = *reinterpret_cast<const float4*>(sq + i0);
        int4  labi = *reinterpret_cast<const int4*>(labels + i0);
        #pragma unroll
        for (int n = 0; n < 4; ++n) {
            int jc = wc + n * 16 + fr;
            #pragma unroll
            for (int r4 = 0; r4 < 4; ++r4) {
                int ir = wr + m * 16 + kg * 4 + r4;
                if (offdiag || jc > ir) {
                    float si = (r4 == 0) ? sqi.x : (r4 == 1) ? sqi.y
                             : (r4 == 2) ? sqi.z : sqi.w;
                    int   li = (r4 == 0) ? labi.x : (r4 == 1) ? labi.y
                             : (r4 == 2) ? labi.z : labi.w;
                    float d2   = fmaf(-2.0f, acc[m][n][r4], si + sqj[n]);
                    float dist = __builtin_amdgcn_sqrtf(fmaxf(d2, 0.0f));
                    float ds   = __builtin_amdgcn_sqrtf(dist + 1e-7f);
                    local += (li == labj[n]) ? ds : fmaxf(1.0f - ds, 0.0f);
                }
            }
        }
    }
    #pragma unroll
    for (int off = 32; off > 0; off >>= 1) local += __shfl_down(local, off);
    if (lane == 0) wsum[w] = local;
    __syncthreads();
    if (t == 0) atomicAdd(accum, wsum[0] + wsum[1] + wsum[2] + wsum[3]);
}

// ---- kernel 3: scale and write scalar output ----
__global__ void finalize_kernel(const float* __restrict__ accum,
                                float* __restrict__ out, double inv_pairs) {
    out[0] = (float)((double)accum[0] * inv_pairs);
}

extern "C" void kernel_launch(void* const* d_in, const int* in_sizes, int n_in,
                              void* d_out, int out_size, void* d_ws, size_t ws_size,
                              hipStream_t stream) {
    const float* emb   = (const float*)d_in[0];
    const int*  labels = (const int*)d_in[1];
    int n  = in_sizes[1];          // 8192
    int nt = n >> 7;               // 128-row tiles

    float*          accum = (float*)d_ws;
    float*          sq    = (float*)((char*)d_ws + 256);
    unsigned short* ebs   = (unsigned short*)((char*)d_ws + 65536);

    hipMemsetAsync(accum, 0, sizeof(float), stream);
    prep_kernel<<<n / 16, 256, 0, stream>>>(emb, ebs, sq, n);

    int nblocks = nt * (nt + 1) / 2;   // upper-triangular tiles incl. diagonal
    loss_kernel<<<nblocks, 256, 0, stream>>>(ebs, labels, sq, accum, nt);

    double inv_pairs = 2.0 / ((double)n * (double)(n - 1));
    finalize_kernel<<<1, 1, 0, stream>>>(accum, (float*)d_out, inv_pairs);
}

// Round 4
// 53.680 us; speedup vs baseline: 1.3693x; 1.3693x over previous
//
#include <hip/hip_runtime.h>
#include <hip/hip_bf16.h>
#include <stdint.h>

typedef __attribute__((ext_vector_type(8))) short short8;
typedef __attribute__((ext_vector_type(4))) float f32x4;

__device__ __forceinline__ unsigned int f2bf(float f) {
    unsigned int u = __float_as_uint(f);
    return (u + 0x7fffu + ((u >> 16) & 1u)) >> 16;   // RNE fp32 -> bf16
}

// ---- kernel 1: fp32 -> bf16 in FRAGMENT-NATIVE layout + row squared norms ----
// Element (row,k) stored at byte  (row>>4)*4096 + (k>>3)*256 + (row&15)*16 + (k&7)*2
// so an MFMA fragment wave-load (lane = kg*16+fr) is base + lane*16: coalesced 1KB.
__global__ void prep_kernel(const float* __restrict__ emb,
                            unsigned short* __restrict__ ebs,
                            float* __restrict__ sq, int n) {
    int t = threadIdx.x;
    int row = blockIdx.x * 16 + (t >> 4);
    int c   = t & 15;                       // k-chunk (8 elems / 16B)
    if (row >= n) return;
    const float* src = emb + (size_t)row * 128 + c * 8;
    float4 f0 = *reinterpret_cast<const float4*>(src);
    float4 f1 = *reinterpret_cast<const float4*>(src + 4);
    uint4 wv;
    wv.x = f2bf(f0.x) | (f2bf(f0.y) << 16);
    wv.y = f2bf(f0.z) | (f2bf(f0.w) << 16);
    wv.z = f2bf(f1.x) | (f2bf(f1.y) << 16);
    wv.w = f2bf(f1.z) | (f2bf(f1.w) << 16);
    size_t byte = (size_t)(row >> 4) * 4096 + c * 256 + (row & 15) * 16;
    *reinterpret_cast<uint4*>(reinterpret_cast<char*>(ebs) + byte) = wv;
    float p = f0.x*f0.x + f0.y*f0.y + f0.z*f0.z + f0.w*f0.w
            + f1.x*f1.x + f1.y*f1.y + f1.z*f1.z + f1.w*f1.w;
    #pragma unroll
    for (int off = 1; off < 16; off <<= 1) p += __shfl_xor(p, off);
    if (c == 0) sq[row] = p;
}

// ---- kernel 2: zero-LDS gram tile + fused loss epilogue ----
// All fragment loads are coalesced 1KB wave-loads straight from L2.
__launch_bounds__(256, 4)
__global__ void loss_kernel(const unsigned short* __restrict__ ebs,
                            const int* __restrict__ labels,
                            const float* __restrict__ sq,
                            float* __restrict__ accum, int nt) {
    __shared__ float wsum[4];

    // linear block id -> upper-triangular tile (bi, bj), bj >= bi
    int tt = blockIdx.x, bi = 0;
    while (tt >= nt - bi) { tt -= nt - bi; ++bi; }
    int bj = bi + tt;
    int rowBase = bi << 7, colBase = bj << 7;
    bool diag = (bi == bj);

    int t = threadIdx.x, lane = t & 63, w = t >> 6;
    int wr = (w >> 1) << 6, wc = (w & 1) << 6;   // 64x64 quadrant per wave
    int fr = lane & 15, kg = lane >> 4;

    const char* base = reinterpret_cast<const char*>(ebs);
    int aT = (rowBase + wr) >> 4;   // 16-row fragment-tile index (+m)
    int bT = (colBase + wc) >> 4;   // (+n)
    int lo = lane << 4;

    f32x4 acc[4][4];
    const f32x4 zero = {0.0f, 0.0f, 0.0f, 0.0f};
    #pragma unroll
    for (int m = 0; m < 4; ++m)
        #pragma unroll
        for (int n = 0; n < 4; ++n) acc[m][n] = zero;

    #pragma unroll
    for (int kk = 0; kk < 4; ++kk) {
        short8 a[4], b[4];
        #pragma unroll
        for (int m = 0; m < 4; ++m)
            a[m] = *reinterpret_cast<const short8*>(
                       base + (size_t)(aT + m) * 4096 + kk * 1024 + lo);
        #pragma unroll
        for (int n = 0; n < 4; ++n)
            b[n] = *reinterpret_cast<const short8*>(
                       base + (size_t)(bT + n) * 4096 + kk * 1024 + lo);
        #pragma unroll
        for (int m = 0; m < 4; ++m)
            #pragma unroll
            for (int n = 0; n < 4; ++n)
                acc[m][n] = __builtin_amdgcn_mfma_f32_16x16x32_bf16(
                                a[m], b[n], acc[m][n], 0, 0, 0);
    }

    // epilogue: C/D layout col=lane&15, row=(lane>>4)*4+reg
    bool offdiag = !diag;
    float sqj[4]; int labj[4];
    #pragma unroll
    for (int n = 0; n < 4; ++n) {
        int j   = colBase + wc + n * 16 + fr;
        sqj[n]  = sq[j];
        labj[n] = labels[j];
    }
    float local = 0.0f;
    #pragma unroll
    for (int m = 0; m < 4; ++m) {
        int i0 = rowBase + wr + m * 16 + kg * 4;   // 4 consecutive rows
        float4 sqi = *reinterpret_cast<const float4*>(sq + i0);
        int4  labi = *reinterpret_cast<const int4*>(labels + i0);
        #pragma unroll
        for (int n = 0; n < 4; ++n) {
            int jc = wc + n * 16 + fr;
            #pragma unroll
            for (int r4 = 0; r4 < 4; ++r4) {
                int ir = wr + m * 16 + kg * 4 + r4;
                if (offdiag || jc > ir) {
                    float si = (r4 == 0) ? sqi.x : (r4 == 1) ? sqi.y
                             : (r4 == 2) ? sqi.z : sqi.w;
                    int   li = (r4 == 0) ? labi.x : (r4 == 1) ? labi.y
                             : (r4 == 2) ? labi.z : labi.w;
                    float d2   = fmaf(-2.0f, acc[m][n][r4], si + sqj[n]);
                    float dist = __builtin_amdgcn_sqrtf(fmaxf(d2, 0.0f));
                    float ds   = __builtin_amdgcn_sqrtf(dist + 1e-7f);
                    local += (li == labj[n]) ? ds : fmaxf(1.0f - ds, 0.0f);
                }
            }
        }
    }
    #pragma unroll
    for (int off = 32; off > 0; off >>= 1) local += __shfl_down(local, off);
    if (lane == 0) wsum[w] = local;
    __syncthreads();
    if (t == 0) atomicAdd(accum, wsum[0] + wsum[1] + wsum[2] + wsum[3]);
}

// ---- kernel 3: scale and write scalar output ----
__global__ void finalize_kernel(const float* __restrict__ accum,
                                float* __restrict__ out, double inv_pairs) {
    out[0] = (float)((double)accum[0] * inv_pairs);
}

extern "C" void kernel_launch(void* const* d_in, const int* in_sizes, int n_in,
                              void* d_out, int out_size, void* d_ws, size_t ws_size,
                              hipStream_t stream) {
    const float* emb   = (const float*)d_in[0];
    const int*  labels = (const int*)d_in[1];
    int n  = in_sizes[1];          // 8192
    int nt = n >> 7;               // 128-row tiles

    float*          accum = (float*)d_ws;
    float*          sq    = (float*)((char*)d_ws + 256);
    unsigned short* ebs   = (unsigned short*)((char*)d_ws + 65536);

    hipMemsetAsync(accum, 0, sizeof(float), stream);
    prep_kernel<<<n / 16, 256, 0, stream>>>(emb, ebs, sq, n);

    int nblocks = nt * (nt + 1) / 2;   // upper-triangular tiles incl. diagonal
    loss_kernel<<<nblocks, 256, 0, stream>>>(ebs, labels, sq, accum, nt);

    double inv_pairs = 2.0 / ((double)n * (double)(n - 1));
    finalize_kernel<<<1, 1, 0, stream>>>(accum, (float*)d_out, inv_pairs);
}

// Round 5
// 51.251 us; speedup vs baseline: 1.4342x; 1.0474x over previous
//
#include <hip/hip_runtime.h>
#include <hip/hip_bf16.h>
#include <stdint.h>

typedef __attribute__((ext_vector_type(8))) short short8;
typedef __attribute__((ext_vector_type(4))) float f32x4;

__device__ __forceinline__ unsigned int f2bf(float f) {
    unsigned int u = __float_as_uint(f);
    return (u + 0x7fffu + ((u >> 16) & 1u)) >> 16;   // RNE fp32 -> bf16
}

// ---- kernel 1: fp32 -> bf16 in FRAGMENT-NATIVE layout + row squared norms ----
// Element (row,k) at byte (row>>4)*4096 + (k>>3)*256 + (row&15)*16 + (k&7)*2.
// A 256-row band is a CONTIGUOUS 64 KB block -> bulk global_load_lds staging.
__global__ void prep_kernel(const float* __restrict__ emb,
                            unsigned short* __restrict__ ebs,
                            float* __restrict__ sq, int n) {
    int t = threadIdx.x;
    int row = blockIdx.x * 16 + (t >> 4);
    int c   = t & 15;                       // k-chunk (8 elems / 16B)
    if (row >= n) return;
    const float* src = emb + (size_t)row * 128 + c * 8;
    float4 f0 = *reinterpret_cast<const float4*>(src);
    float4 f1 = *reinterpret_cast<const float4*>(src + 4);
    uint4 wv;
    wv.x = f2bf(f0.x) | (f2bf(f0.y) << 16);
    wv.y = f2bf(f0.z) | (f2bf(f0.w) << 16);
    wv.z = f2bf(f1.x) | (f2bf(f1.y) << 16);
    wv.w = f2bf(f1.z) | (f2bf(f1.w) << 16);
    size_t byte = (size_t)(row >> 4) * 4096 + c * 256 + (row & 15) * 16;
    *reinterpret_cast<uint4*>(reinterpret_cast<char*>(ebs) + byte) = wv;
    float p = f0.x*f0.x + f0.y*f0.y + f0.z*f0.z + f0.w*f0.w
            + f1.x*f1.x + f1.y*f1.y + f1.z*f1.z + f1.w*f1.w;
    #pragma unroll
    for (int off = 1; off < 16; off <<= 1) p += __shfl_xor(p, off);
    if (c == 0) sq[row] = p;
}

// ---- kernel 2: 256x256 LDS-staged gram tile + fused loss epilogue ----
// 512 threads = 8 waves, each computing a 64x128 sub-tile (acc[4][8]).
__launch_bounds__(512, 2)
__global__ void loss_kernel(const unsigned short* __restrict__ ebs,
                            const int* __restrict__ labels,
                            const float* __restrict__ sq,
                            float* __restrict__ accum, int nt) {
    __shared__ __align__(16) char As[65536];
    __shared__ __align__(16) char Bs[65536];
    __shared__ float wsum[8];

    // linear block id -> upper-triangular tile (bi, bj), bj >= bi
    int tt = blockIdx.x, bi = 0;
    while (tt >= nt - bi) { tt -= nt - bi; ++bi; }
    int bj = bi + tt;
    int rowBase = bi << 8, colBase = bj << 8;
    bool diag = (bi == bj);

    int t = threadIdx.x, lane = t & 63, w = t >> 6;

    // stage contiguous 64 KB band(s) into LDS (each wave: 8 x 1KB chunks)
    {
        const char* gA = reinterpret_cast<const char*>(ebs) + (size_t)rowBase * 256;
        const char* gB = reinterpret_cast<const char*>(ebs) + (size_t)colBase * 256;
        int laneOff = lane << 4;
        int wbase = w << 13;                   // w * 8 KB
        #pragma unroll
        for (int it = 0; it < 8; ++it) {
            int off = wbase + (it << 10);
            __builtin_amdgcn_global_load_lds(
                (const __attribute__((address_space(1))) void*)(gA + off + laneOff),
                (__attribute__((address_space(3))) void*)(As + off), 16, 0, 0);
        }
        if (!diag) {
            #pragma unroll
            for (int it = 0; it < 8; ++it) {
                int off = wbase + (it << 10);
                __builtin_amdgcn_global_load_lds(
                    (const __attribute__((address_space(1))) void*)(gB + off + laneOff),
                    (__attribute__((address_space(3))) void*)(Bs + off), 16, 0, 0);
            }
        }
    }
    __syncthreads();

    int wr = (w >> 1) << 6;        // 0,64,128,192
    int wc = (w & 1) << 7;         // 0,128
    int fr = lane & 15, kg = lane >> 4;
    const char* Ab = As;
    const char* Bb = diag ? As : Bs;
    int aOff = (wr >> 4) * 4096 + lane * 16;   // + m*4096 + kk*1024
    int bOff = (wc >> 4) * 4096 + lane * 16;   // + n*4096 + kk*1024

    f32x4 acc[4][8];
    const f32x4 zero = {0.0f, 0.0f, 0.0f, 0.0f};
    #pragma unroll
    for (int m = 0; m < 4; ++m)
        #pragma unroll
        for (int n = 0; n < 8; ++n) acc[m][n] = zero;

    #pragma unroll
    for (int kk = 0; kk < 4; ++kk) {
        short8 a[4], b[8];
        #pragma unroll
        for (int m = 0; m < 4; ++m)
            a[m] = *reinterpret_cast<const short8*>(Ab + aOff + m * 4096 + kk * 1024);
        #pragma unroll
        for (int n = 0; n < 8; ++n)
            b[n] = *reinterpret_cast<const short8*>(Bb + bOff + n * 4096 + kk * 1024);
        #pragma unroll
        for (int m = 0; m < 4; ++m)
            #pragma unroll
            for (int n = 0; n < 8; ++n)
                acc[m][n] = __builtin_amdgcn_mfma_f32_16x16x32_bf16(
                                a[m], b[n], acc[m][n], 0, 0, 0);
    }

    // fused epilogue: C/D layout col=lane&15, row=(lane>>4)*4+reg
    bool offdiag = !diag;
    float sqj[8]; int labj[8];
    #pragma unroll
    for (int n = 0; n < 8; ++n) {
        int j   = colBase + wc + n * 16 + fr;
        sqj[n]  = sq[j];
        labj[n] = labels[j];
    }
    float local = 0.0f;
    #pragma unroll
    for (int m = 0; m < 4; ++m) {
        int i0 = rowBase + wr + m * 16 + kg * 4;   // 4 consecutive rows
        float4 sqi = *reinterpret_cast<const float4*>(sq + i0);
        int4  labi = *reinterpret_cast<const int4*>(labels + i0);
        #pragma unroll
        for (int n = 0; n < 8; ++n) {
            int jc = wc + n * 16 + fr;
            #pragma unroll
            for (int r4 = 0; r4 < 4; ++r4) {
                int ir = wr + m * 16 + kg * 4 + r4;
                if (offdiag || jc > ir) {
                    float si = (r4 == 0) ? sqi.x : (r4 == 1) ? sqi.y
                             : (r4 == 2) ? sqi.z : sqi.w;
                    int   li = (r4 == 0) ? labi.x : (r4 == 1) ? labi.y
                             : (r4 == 2) ? labi.z : labi.w;
                    float d2   = fmaf(-2.0f, acc[m][n][r4], si + sqj[n]);
                    float dist = __builtin_amdgcn_sqrtf(fmaxf(d2, 0.0f));
                    float ds   = __builtin_amdgcn_sqrtf(dist + 1e-7f);
                    local += (li == labj[n]) ? ds : fmaxf(1.0f - ds, 0.0f);
                }
            }
        }
    }
    #pragma unroll
    for (int off = 32; off > 0; off >>= 1) local += __shfl_down(local, off);
    if (lane == 0) wsum[w] = local;
    __syncthreads();
    if (t == 0) {
        float s = 0.0f;
        #pragma unroll
        for (int i = 0; i < 8; ++i) s += wsum[i];
        atomicAdd(accum, s);
    }
}

// ---- kernel 3: scale and write scalar output ----
__global__ void finalize_kernel(const float* __restrict__ accum,
                                float* __restrict__ out, double inv_pairs) {
    out[0] = (float)((double)accum[0] * inv_pairs);
}

extern "C" void kernel_launch(void* const* d_in, const int* in_sizes, int n_in,
                              void* d_out, int out_size, void* d_ws, size_t ws_size,
                              hipStream_t stream) {
    const float* emb   = (const float*)d_in[0];
    const int*  labels = (const int*)d_in[1];
    int n   = in_sizes[1];         // 8192
    int nt2 = n >> 8;              // 256-row tiles -> 32

    float*          accum = (float*)d_ws;
    float*          sq    = (float*)((char*)d_ws + 256);
    unsigned short* ebs   = (unsigned short*)((char*)d_ws + 65536);

    hipMemsetAsync(accum, 0, sizeof(float), stream);
    prep_kernel<<<n / 16, 256, 0, stream>>>(emb, ebs, sq, n);

    int nblocks = nt2 * (nt2 + 1) / 2;   // upper-triangular tiles incl. diagonal
    loss_kernel<<<nblocks, 512, 0, stream>>>(ebs, labels, sq, accum, nt2);

    double inv_pairs = 2.0 / ((double)n * (double)(n - 1));
    finalize_kernel<<<1, 1, 0, stream>>>(accum, (float*)d_out, inv_pairs);
}

// Round 6
// 50.232 us; speedup vs baseline: 1.4633x; 1.0203x over previous
//
#include <hip/hip_runtime.h>
#include <hip/hip_bf16.h>
#include <stdint.h>

typedef __attribute__((ext_vector_type(8))) short short8;
typedef __attribute__((ext_vector_type(4))) float f32x4;

__device__ __forceinline__ unsigned int f2bf(float f) {
    unsigned int u = __float_as_uint(f);
    return (u + 0x7fffu + ((u >> 16) & 1u)) >> 16;   // RNE fp32 -> bf16
}

// ---- kernel 1: fp32 -> bf16 in FRAGMENT-NATIVE layout + row squared norms ----
// Element (row,k) at byte (row>>4)*4096 + (k>>3)*256 + (row&15)*16 + (k&7)*2.
// A 256-row band is a CONTIGUOUS 64 KB block -> bulk global_load_lds staging.
__global__ void prep_kernel(const float* __restrict__ emb,
                            unsigned short* __restrict__ ebs,
                            float* __restrict__ sq, int n) {
    int t = threadIdx.x;
    int row = blockIdx.x * 16 + (t >> 4);
    int c   = t & 15;                       // k-chunk (8 elems / 16B)
    if (row >= n) return;
    const float* src = emb + (size_t)row * 128 + c * 8;
    float4 f0 = *reinterpret_cast<const float4*>(src);
    float4 f1 = *reinterpret_cast<const float4*>(src + 4);
    uint4 wv;
    wv.x = f2bf(f0.x) | (f2bf(f0.y) << 16);
    wv.y = f2bf(f0.z) | (f2bf(f0.w) << 16);
    wv.z = f2bf(f1.x) | (f2bf(f1.y) << 16);
    wv.w = f2bf(f1.z) | (f2bf(f1.w) << 16);
    size_t byte = (size_t)(row >> 4) * 4096 + c * 256 + (row & 15) * 16;
    *reinterpret_cast<uint4*>(reinterpret_cast<char*>(ebs) + byte) = wv;
    float p = f0.x*f0.x + f0.y*f0.y + f0.z*f0.z + f0.w*f0.w
            + f1.x*f1.x + f1.y*f1.y + f1.z*f1.z + f1.w*f1.w;
    #pragma unroll
    for (int off = 1; off < 16; off <<= 1) p += __shfl_xor(p, off);
    if (c == 0) sq[row] = p;
}

// ---- kernel 2: 256x256 LDS-staged gram tile, 16 waves (4/SIMD) ----
// Each wave: 64x64 quadrant, computed as two 32x64 halves (32 AGPR each).
__launch_bounds__(1024)
__global__ void loss_kernel(const unsigned short* __restrict__ ebs,
                            const int* __restrict__ labels,
                            const float* __restrict__ sq,
                            float* __restrict__ accum, int nt) {
    __shared__ __align__(16) char As[65536];
    __shared__ __align__(16) char Bs[65536];
    __shared__ float wsum[16];

    // linear block id -> upper-triangular tile (bi, bj), bj >= bi
    int tt = blockIdx.x, bi = 0;
    while (tt >= nt - bi) { tt -= nt - bi; ++bi; }
    int bj = bi + tt;
    int rowBase = bi << 8, colBase = bj << 8;
    bool diag = (bi == bj);

    int t = threadIdx.x, lane = t & 63, w = t >> 6;

    // stage contiguous 64 KB band(s): 1024 threads x 16B = 16KB per sweep
    {
        const char* gA = reinterpret_cast<const char*>(ebs) + (size_t)rowBase * 256;
        const char* gB = reinterpret_cast<const char*>(ebs) + (size_t)colBase * 256;
        int thrOff = t << 4;                   // (w<<10 wave-uniform) + lane*16
        #pragma unroll
        for (int it = 0; it < 4; ++it) {
            int off = (it << 14) + thrOff;
            __builtin_amdgcn_global_load_lds(
                (const __attribute__((address_space(1))) void*)(gA + off),
                (__attribute__((address_space(3))) void*)(As + off), 16, 0, 0);
        }
        if (!diag) {
            #pragma unroll
            for (int it = 0; it < 4; ++it) {
                int off = (it << 14) + thrOff;
                __builtin_amdgcn_global_load_lds(
                    (const __attribute__((address_space(1))) void*)(gB + off),
                    (__attribute__((address_space(3))) void*)(Bs + off), 16, 0, 0);
            }
        }
    }
    __syncthreads();

    int wr = (w >> 2) << 6;        // 0,64,128,192
    int wc = (w & 3) << 6;         // 0,64,128,192
    int fr = lane & 15, kg = lane >> 4;
    const char* Ab = As;
    const char* Bb = diag ? As : Bs;
    int lo = lane << 4;

    bool offdiag = !diag;
    float sqj[4]; int labj[4];
    #pragma unroll
    for (int n = 0; n < 4; ++n) {
        int j   = colBase + wc + n * 16 + fr;
        sqj[n]  = sq[j];
        labj[n] = labels[j];
    }

    float local = 0.0f;
    #pragma unroll
    for (int mh = 0; mh < 2; ++mh) {              // two 32x64 halves
        int aT = (wr >> 4) + mh * 2;              // fragment-tile row index (+m2)
        f32x4 acc[2][4];
        const f32x4 zero = {0.0f, 0.0f, 0.0f, 0.0f};
        #pragma unroll
        for (int m = 0; m < 2; ++m)
            #pragma unroll
            for (int n = 0; n < 4; ++n) acc[m][n] = zero;

        #pragma unroll
        for (int kk = 0; kk < 4; ++kk) {
            short8 a[2], b[4];
            #pragma unroll
            for (int m = 0; m < 2; ++m)
                a[m] = *reinterpret_cast<const short8*>(
                           Ab + (aT + m) * 4096 + kk * 1024 + lo);
            #pragma unroll
            for (int n = 0; n < 4; ++n)
                b[n] = *reinterpret_cast<const short8*>(
                           Bb + ((wc >> 4) + n) * 4096 + kk * 1024 + lo);
            #pragma unroll
            for (int m = 0; m < 2; ++m)
                #pragma unroll
                for (int n = 0; n < 4; ++n)
                    acc[m][n] = __builtin_amdgcn_mfma_f32_16x16x32_bf16(
                                    a[m], b[n], acc[m][n], 0, 0, 0);
        }

        // fused epilogue: C/D layout col=lane&15, row=(lane>>4)*4+reg
        float l0 = 0.0f, l1 = 0.0f, l2 = 0.0f, l3 = 0.0f;
        #pragma unroll
        for (int m = 0; m < 2; ++m) {
            int irb = wr + mh * 32 + m * 16 + kg * 4;  // 4 consecutive rows
            float4 sqi = *reinterpret_cast<const float4*>(sq + rowBase + irb);
            int4  labi = *reinterpret_cast<const int4*>(labels + rowBase + irb);
            #pragma unroll
            for (int n = 0; n < 4; ++n) {
                int jc = wc + n * 16 + fr;
                #pragma unroll
                for (int r4 = 0; r4 < 4; ++r4) {
                    int ir = irb + r4;
                    if (offdiag || jc > ir) {
                        float si = (r4 == 0) ? sqi.x : (r4 == 1) ? sqi.y
                                 : (r4 == 2) ? sqi.z : sqi.w;
                        int   li = (r4 == 0) ? labi.x : (r4 == 1) ? labi.y
                                 : (r4 == 2) ? labi.z : labi.w;
                        float d2   = fmaf(-2.0f, acc[m][n][r4], si + sqj[n]);
                        float dist = __builtin_amdgcn_sqrtf(fmaxf(d2, 0.0f));
                        float ds   = __builtin_amdgcn_sqrtf(dist + 1e-7f);
                        float v    = (li == labj[n]) ? ds : fmaxf(1.0f - ds, 0.0f);
                        if      (r4 == 0) l0 += v;
                        else if (r4 == 1) l1 += v;
                        else if (r4 == 2) l2 += v;
                        else              l3 += v;
                    }
                }
            }
        }
        local += (l0 + l1) + (l2 + l3);
    }

    #pragma unroll
    for (int off = 32; off > 0; off >>= 1) local += __shfl_down(local, off);
    if (lane == 0) wsum[w] = local;
    __syncthreads();
    if (t == 0) {
        float s = 0.0f;
        #pragma unroll
        for (int i = 0; i < 16; ++i) s += wsum[i];
        atomicAdd(accum, s);
    }
}

// ---- kernel 3: scale and write scalar output ----
__global__ void finalize_kernel(const float* __restrict__ accum,
                                float* __restrict__ out, double inv_pairs) {
    out[0] = (float)((double)accum[0] * inv_pairs);
}

extern "C" void kernel_launch(void* const* d_in, const int* in_sizes, int n_in,
                              void* d_out, int out_size, void* d_ws, size_t ws_size,
                              hipStream_t stream) {
    const float* emb   = (const float*)d_in[0];
    const int*  labels = (const int*)d_in[1];
    int n   = in_sizes[1];         // 8192
    int nt2 = n >> 8;              // 256-row tiles -> 32

    float*          accum = (float*)d_ws;
    float*          sq    = (float*)((char*)d_ws + 256);
    unsigned short* ebs   = (unsigned short*)((char*)d_ws + 65536);

    hipMemsetAsync(accum, 0, sizeof(float), stream);
    prep_kernel<<<n / 16, 256, 0, stream>>>(emb, ebs, sq, n);

    int nblocks = nt2 * (nt2 + 1) / 2;   // upper-triangular tiles incl. diagonal
    loss_kernel<<<nblocks, 1024, 0, stream>>>(ebs, labels, sq, accum, nt2);

    double inv_pairs = 2.0 / ((double)n * (double)(n - 1));
    finalize_kernel<<<1, 1, 0, stream>>>(accum, (float*)d_out, inv_pairs);
}

// Round 7
// 48.586 us; speedup vs baseline: 1.5128x; 1.0339x over previous
//
#include <hip/hip_runtime.h>
#include <hip/hip_bf16.h>
#include <stdint.h>

typedef __attribute__((ext_vector_type(8))) short short8;
typedef __attribute__((ext_vector_type(4))) float f32x4;

__device__ __forceinline__ unsigned int f2bf(float f) {
    unsigned int u = __float_as_uint(f);
    return (u + 0x7fffu + ((u >> 16) & 1u)) >> 16;   // RNE fp32 -> bf16
}

// ---- kernel 1: fp32 -> bf16 in FRAGMENT-NATIVE layout + row squared norms ----
// Element (row,k) at byte (row>>4)*4096 + (k>>3)*256 + (row&15)*16 + (k&7)*2.
// Any 128-row band is a CONTIGUOUS 32 KB block -> bulk global_load_lds staging.
__global__ void prep_kernel(const float* __restrict__ emb,
                            unsigned short* __restrict__ ebs,
                            float* __restrict__ sq, int n) {
    int t = threadIdx.x;
    int row = blockIdx.x * 16 + (t >> 4);
    int c   = t & 15;                       // k-chunk (8 elems / 16B)
    if (row >= n) return;
    const float* src = emb + (size_t)row * 128 + c * 8;
    float4 f0 = *reinterpret_cast<const float4*>(src);
    float4 f1 = *reinterpret_cast<const float4*>(src + 4);
    uint4 wv;
    wv.x = f2bf(f0.x) | (f2bf(f0.y) << 16);
    wv.y = f2bf(f0.z) | (f2bf(f0.w) << 16);
    wv.z = f2bf(f1.x) | (f2bf(f1.y) << 16);
    wv.w = f2bf(f1.z) | (f2bf(f1.w) << 16);
    size_t byte = (size_t)(row >> 4) * 4096 + c * 256 + (row & 15) * 16;
    *reinterpret_cast<uint4*>(reinterpret_cast<char*>(ebs) + byte) = wv;
    float p = f0.x*f0.x + f0.y*f0.y + f0.z*f0.z + f0.w*f0.w
            + f1.x*f1.x + f1.y*f1.y + f1.z*f1.z + f1.w*f1.w;
    #pragma unroll
    for (int off = 1; off < 16; off <<= 1) p += __shfl_xor(p, off);
    if (c == 0) sq[row] = p;
}

// ---- kernel 2: 128x128 LDS tile, 8 waves of 32x64, 2 blocks/CU ----
__launch_bounds__(512, 4)
__global__ void loss_kernel(const unsigned short* __restrict__ ebs,
                            const int* __restrict__ labels,
                            const float* __restrict__ sq,
                            float* __restrict__ accum, int nt) {
    __shared__ __align__(16) char As[32768];
    __shared__ __align__(16) char Bs[32768];
    __shared__ float wsum[8];

    // linear block id -> upper-triangular tile (bi, bj), bj >= bi
    int tt = blockIdx.x, bi = 0;
    while (tt >= nt - bi) { tt -= nt - bi; ++bi; }
    int bj = bi + tt;
    int rowBase = bi << 7, colBase = bj << 7;
    bool diag = (bi == bj);

    int t = threadIdx.x, lane = t & 63, w = t >> 6;

    // stage 32 KB band(s): 512 threads x 16B = 8 KB per sweep
    {
        const char* gA = reinterpret_cast<const char*>(ebs) + (size_t)rowBase * 256;
        int thrOff = t << 4;
        #pragma unroll
        for (int it = 0; it < 4; ++it) {
            int off = (it << 13) + thrOff;
            __builtin_amdgcn_global_load_lds(
                (const __attribute__((address_space(1))) void*)(gA + off),
                (__attribute__((address_space(3))) void*)(As + off), 16, 0, 0);
        }
        if (!diag) {
            const char* gB = reinterpret_cast<const char*>(ebs) + (size_t)colBase * 256;
            #pragma unroll
            for (int it = 0; it < 4; ++it) {
                int off = (it << 13) + thrOff;
                __builtin_amdgcn_global_load_lds(
                    (const __attribute__((address_space(1))) void*)(gB + off),
                    (__attribute__((address_space(3))) void*)(Bs + off), 16, 0, 0);
            }
        }
    }
    __syncthreads();

    int wr = (w & 3) << 5;         // 0,32,64,96   (32-row strip)
    int wc = (w >> 2) << 6;        // 0,64         (64-col strip)
    int fr = lane & 15, kg = lane >> 4;
    const char* Ab = As;
    const char* Bb = diag ? As : Bs;
    int lo = lane << 4;
    int aT = wr >> 4;              // fragment-tile indices
    int bT = wc >> 4;

    f32x4 acc[2][4];
    const f32x4 zero = {0.0f, 0.0f, 0.0f, 0.0f};
    #pragma unroll
    for (int m = 0; m < 2; ++m)
        #pragma unroll
        for (int n = 0; n < 4; ++n) acc[m][n] = zero;

    #pragma unroll
    for (int kk = 0; kk < 4; ++kk) {
        short8 a[2], b[4];
        #pragma unroll
        for (int m = 0; m < 2; ++m)
            a[m] = *reinterpret_cast<const short8*>(
                       Ab + (aT + m) * 4096 + kk * 1024 + lo);
        #pragma unroll
        for (int n = 0; n < 4; ++n)
            b[n] = *reinterpret_cast<const short8*>(
                       Bb + (bT + n) * 4096 + kk * 1024 + lo);
        #pragma unroll
        for (int m = 0; m < 2; ++m)
            #pragma unroll
            for (int n = 0; n < 4; ++n)
                acc[m][n] = __builtin_amdgcn_mfma_f32_16x16x32_bf16(
                                a[m], b[n], acc[m][n], 0, 0, 0);
    }

    // fused epilogue: C/D layout col=lane&15, row=(lane>>4)*4+reg
    bool offdiag = !diag;
    float sqj[4]; int labj[4];
    #pragma unroll
    for (int n = 0; n < 4; ++n) {
        int j   = colBase + wc + n * 16 + fr;
        sqj[n]  = sq[j];
        labj[n] = labels[j];
    }
    float l0 = 0.0f, l1 = 0.0f, l2 = 0.0f, l3 = 0.0f;
    #pragma unroll
    for (int m = 0; m < 2; ++m) {
        int irb = wr + m * 16 + kg * 4;            // 4 consecutive rows
        float4 sqi = *reinterpret_cast<const float4*>(sq + rowBase + irb);
        int4  labi = *reinterpret_cast<const int4*>(labels + rowBase + irb);
        #pragma unroll
        for (int n = 0; n < 4; ++n) {
            int jc = wc + n * 16 + fr;
            #pragma unroll
            for (int r4 = 0; r4 < 4; ++r4) {
                int ir = irb + r4;
                if (offdiag || jc > ir) {
                    float si = (r4 == 0) ? sqi.x : (r4 == 1) ? sqi.y
                             : (r4 == 2) ? sqi.z : sqi.w;
                    int   li = (r4 == 0) ? labi.x : (r4 == 1) ? labi.y
                             : (r4 == 2) ? labi.z : labi.w;
                    float d2   = fmaf(-2.0f, acc[m][n][r4], si + sqj[n]);
                    float dist = __builtin_amdgcn_sqrtf(fmaxf(d2, 0.0f));
                    float ds   = __builtin_amdgcn_sqrtf(dist + 1e-7f);
                    float v    = (li == labj[n]) ? ds : fmaxf(1.0f - ds, 0.0f);
                    if      (r4 == 0) l0 += v;
                    else if (r4 == 1) l1 += v;
                    else if (r4 == 2) l2 += v;
                    else              l3 += v;
                }
            }
        }
    }
    float local = (l0 + l1) + (l2 + l3);

    #pragma unroll
    for (int off = 32; off > 0; off >>= 1) local += __shfl_down(local, off);
    if (lane == 0) wsum[w] = local;
    __syncthreads();
    if (t == 0) {
        float s = 0.0f;
        #pragma unroll
        for (int i = 0; i < 8; ++i) s += wsum[i];
        atomicAdd(accum, s);
    }
}

// ---- kernel 3: scale and write scalar output ----
__global__ void finalize_kernel(const float* __restrict__ accum,
                                float* __restrict__ out, double inv_pairs) {
    out[0] = (float)((double)accum[0] * inv_pairs);
}

extern "C" void kernel_launch(void* const* d_in, const int* in_sizes, int n_in,
                              void* d_out, int out_size, void* d_ws, size_t ws_size,
                              hipStream_t stream) {
    const float* emb   = (const float*)d_in[0];
    const int*  labels = (const int*)d_in[1];
    int n  = in_sizes[1];          // 8192
    int nt = n >> 7;               // 128-row tiles -> 64

    float*          accum = (float*)d_ws;
    float*          sq    = (float*)((char*)d_ws + 256);
    unsigned short* ebs   = (unsigned short*)((char*)d_ws + 65536);

    hipMemsetAsync(accum, 0, sizeof(float), stream);
    prep_kernel<<<n / 16, 256, 0, stream>>>(emb, ebs, sq, n);

    int nblocks = nt * (nt + 1) / 2;   // upper-triangular tiles incl. diagonal
    loss_kernel<<<nblocks, 512, 0, stream>>>(ebs, labels, sq, accum, nt);

    double inv_pairs = 2.0 / ((double)n * (double)(n - 1));
    finalize_kernel<<<1, 1, 0, stream>>>(accum, (float*)d_out, inv_pairs);
}